// Round 2
// baseline (105.949 us; speedup 1.0000x reference)
//
#include <hip/hip_runtime.h>
#include <hip/hip_bf16.h>

// Fused per-object-type output projection:
//   out[b, f, t] = mask(f < jc[e]*6) * ( sum_d X[t,b,d] * W[e,d,f] + bias[e,f] ),  e = object_types[b]
// Per-sample GEMM: M=768 feats, N=196 frames (pad 224), K=1024, bf16 MFMA, f32 accum.
// Block: BM=96 x full-N 224, BK=32, 4 waves (2x2), wave tile 48x112.

#define NFRAMES 196
#define TPAD    224
#define BSZ     128
#define DLAT    1024
#define FIN     768
#define BM      96
#define BK      32
#define KSTEPS  (DLAT / BK)   // 32
#define MTILES  (FIN / BM)    // 8
#define NTHREADS 256

typedef short bf16x8 __attribute__((ext_vector_type(8)));
typedef short s16x8  __attribute__((ext_vector_type(8)));
typedef short s16x4  __attribute__((ext_vector_type(4)));
typedef float f32x4  __attribute__((ext_vector_type(4)));

// Row swizzle (2 bits): spreads 16-consecutive-row accesses and strided writes
// uniformly over the 4 16B chunks of a 64B row. Verified by enumeration:
// frag reads (16 rows x 4 chunks) -> 8 accesses/bank (b128 floor);
// B writes (16 rows x 4 ko)      -> 8 accesses/bank (b128 floor);
// A writes (24 mb x 2 kb, b64)   -> 3 accesses/bank (floor for 48 lanes).
__device__ __forceinline__ int swz(int r) { return ((r >> 1) & 3) ^ ((r >> 3) & 3); }

__device__ __forceinline__ short f2bf(float f) {
    __hip_bfloat16 h = __float2bfloat16(f);   // RNE
    return __builtin_bit_cast(short, h);
}

// barrier that does NOT drain vmcnt (keeps prefetch global loads in flight)
#define BAR() do { asm volatile("s_waitcnt lgkmcnt(0)" ::: "memory"); \
                   __builtin_amdgcn_s_barrier(); } while (0)

__global__ __launch_bounds__(NTHREADS, 2)
void fused_expert_gemm(const float* __restrict__ X,      // (196,128,1024)
                       const int*   __restrict__ otypes, // (128)
                       const float* __restrict__ W,      // (16,1024,768)
                       const float* __restrict__ Bias,   // (16,768)
                       const int*   __restrict__ jc,     // (16)
                       float*       __restrict__ out)    // (128,768,196)
{
    __shared__ short As[BM * BK];    // [m][k], 64B rows, chunk-swizzled
    __shared__ short Bs[TPAD * BK];  // [t][k], 64B rows, chunk-swizzled

    // XCD chunk swizzle: 1024 blocks, 128 consecutive logical (=16 samples) per XCD.
    const int hw      = blockIdx.x;
    const int logical = (hw & 7) * ((MTILES * BSZ) / 8) + (hw >> 3);
    const int b       = logical >> 3;   // sample
    const int mt      = logical & 7;    // M-tile
    const int m0      = mt * BM;

    const int tid  = threadIdx.x;
    const int e    = otypes[b];
    const int wave = tid >> 6;
    const int lane = tid & 63;
    const int lr   = lane & 15;
    const int g    = (lane >> 4) & 3;
    const int wr   = wave >> 1;   // 0..1 -> M half
    const int wc   = wave & 1;    // 0..1 -> N half

    // A staging: threads with (tid&31)<24 own a 4k x 4m micro-block
    const int mb   = tid & 31;
    const int kb   = tid >> 5;        // k = 4*kb + i
    const bool aact = (mb < 24);
    // B staging: thread owns 8 k of one row; 4 passes x 64 rows
    const int ko = tid & 3;           // k chunk = 8*ko
    const int rw = tid >> 2;          // 0..63

    const f32x4* __restrict__ Xv = reinterpret_cast<const f32x4*>(X);
    const f32x4* __restrict__ Wv = reinterpret_cast<const f32x4*>(W);
    const f32x4 fz = {0.f, 0.f, 0.f, 0.f};

    f32x4 wa[4];      // prefetched W (4 k-rows x 4 m)
    f32x4 xb[4][2];   // prefetched X (4 passes x 8 k)

    // Precomputed LDS read addresses (in shorts)
    int idxA[3], idxB[7];
    #pragma unroll
    for (int f = 0; f < 3; ++f) {
        const int ma = wr * 48 + f * 16 + lr;
        idxA[f] = ma * BK + 8 * (g ^ swz(ma));
    }
    #pragma unroll
    for (int nf = 0; nf < 7; ++nf) {
        const int nr = wc * 112 + nf * 16 + lr;
        idxB[nf] = nr * BK + 8 * (g ^ swz(nr));
    }
    // Precomputed LDS write addresses
    int idxAw[4];
    #pragma unroll
    for (int j = 0; j < 4; ++j) {
        const int r = (mb + j) & 3;
        const int m = mb * 4 + r;
        idxAw[j] = m * BK + 8 * (((kb >> 1) & 3) ^ swz(m)) + (kb & 1) * 4;
    }
    int idxBw[4];
    #pragma unroll
    for (int p = 0; p < 4; ++p) {
        const int n = p * 64 + rw;
        idxBw[p] = n * BK + 8 * (ko ^ swz(n));
    }

    f32x4 acc[3][7];
    #pragma unroll
    for (int f = 0; f < 3; ++f)
        #pragma unroll
        for (int nf = 0; nf < 7; ++nf) acc[f][nf] = fz;

    auto load_stage = [&](int kk) {
        if (aact) {
            #pragma unroll
            for (int i = 0; i < 4; ++i)
                wa[i] = Wv[(e * DLAT + kk + kb * 4 + i) * (FIN / 4) + (m0 >> 2) + mb];
        }
        #pragma unroll
        for (int p = 0; p < 4; ++p) {
            const int n = p * 64 + rw;
            if (n < NFRAMES) {
                const int base = (n * BSZ + b) * (DLAT / 4) + (kk >> 2) + ko * 2;
                xb[p][0] = Xv[base];
                xb[p][1] = Xv[base + 1];
            } else {
                xb[p][0] = fz; xb[p][1] = fz;
            }
        }
    };

    auto write_stage = [&]() {
        if (aact) {
            #pragma unroll
            for (int j = 0; j < 4; ++j) {
                const int r = (mb + j) & 3;
                s16x4 v;
                v[0] = f2bf(wa[0][r]); v[1] = f2bf(wa[1][r]);
                v[2] = f2bf(wa[2][r]); v[3] = f2bf(wa[3][r]);
                *reinterpret_cast<s16x4*>(&As[idxAw[j]]) = v;
            }
        }
        #pragma unroll
        for (int p = 0; p < 4; ++p) {
            if (p * 64 + rw < TPAD) {
                s16x8 v;
                v[0] = f2bf(xb[p][0][0]); v[1] = f2bf(xb[p][0][1]);
                v[2] = f2bf(xb[p][0][2]); v[3] = f2bf(xb[p][0][3]);
                v[4] = f2bf(xb[p][1][0]); v[5] = f2bf(xb[p][1][1]);
                v[6] = f2bf(xb[p][1][2]); v[7] = f2bf(xb[p][1][3]);
                *reinterpret_cast<s16x8*>(&Bs[idxBw[p]]) = v;
            }
        }
    };

    load_stage(0);

    #pragma unroll 1
    for (int ks = 0; ks < KSTEPS; ++ks) {
        BAR();                 // prior compute's LDS reads done (per-wave lgkmcnt + barrier)
        write_stage();         // regs -> LDS (compiler inserts vmcnt waits on reg uses)
        if (ks + 1 < KSTEPS)
            load_stage((ks + 1) * BK);   // issue next tile's global loads early
        BAR();                 // LDS writes visible; vmcnt stays in flight

        bf16x8 af[3];
        #pragma unroll
        for (int f = 0; f < 3; ++f)
            af[f] = *reinterpret_cast<const bf16x8*>(&As[idxA[f]]);
        #pragma unroll
        for (int nf = 0; nf < 7; ++nf) {
            bf16x8 bv = *reinterpret_cast<const bf16x8*>(&Bs[idxB[nf]]);
            #pragma unroll
            for (int f = 0; f < 3; ++f)
                acc[f][nf] = __builtin_amdgcn_mfma_f32_16x16x32_bf16(af[f], bv, acc[f][nf], 0, 0, 0);
        }
    }

    // Epilogue: bias + column mask; write all valid (t<196) outputs (buffer poisoned)
    const int    fcb   = jc[e] * 6;
    const float* biasE = Bias + e * FIN;
    float*       outB  = out + (size_t)b * (FIN * NFRAMES);

    #pragma unroll
    for (int f = 0; f < 3; ++f) {
        #pragma unroll
        for (int rr = 0; rr < 4; ++rr) {
            const int fcol  = m0 + wr * 48 + f * 16 + g * 4 + rr;  // C row = (lane>>4)*4 + reg
            const float bv  = biasE[fcol];
            const bool  val = fcol < fcb;
            #pragma unroll
            for (int nf = 0; nf < 7; ++nf) {
                const int t = wc * 112 + nf * 16 + lr;             // C col = lane&15
                if (t < NFRAMES)
                    outB[fcol * NFRAMES + t] = val ? (acc[f][nf][rr] + bv) : 0.f;
            }
        }
    }
}

extern "C" void kernel_launch(void* const* d_in, const int* in_sizes, int n_in,
                              void* d_out, int out_size, void* d_ws, size_t ws_size,
                              hipStream_t stream) {
    const float* X    = (const float*)d_in[0];
    const int*   ot   = (const int*)d_in[1];
    const float* W    = (const float*)d_in[2];
    const float* Bias = (const float*)d_in[3];
    const int*   jc   = (const int*)d_in[4];
    float*       out  = (float*)d_out;

    dim3 grid(MTILES * BSZ);   // 1024 blocks = 128 samples x 8 M-tiles
    dim3 block(NTHREADS);
    hipLaunchKernelGGL(fused_expert_gemm, grid, block, 0, stream,
                       X, ot, W, Bias, jc, out);
}

// Round 4
// 104.638 us; speedup vs baseline: 1.0125x; 1.0125x over previous
//
#include <hip/hip_runtime.h>
#include <hip/hip_bf16.h>

// Fused per-object-type output projection:
//   out[b, f, t] = mask(f < jc[e]*6) * ( sum_d X[t,b,d] * W[e,d,f] + bias[e,f] ),  e = object_types[b]
// Per-sample GEMM: M=768, N=196 (pad 208), K=1024, bf16 MFMA, f32 accum.
// BM=128 x full-N 208, BK=32, 4 waves (2M x 2N), wave tile 64 x 112/96.
// Masked M-tiles (m0 >= jc[e]*6) early-out with a zero-fill (saves ~40% of compute + W fetch).

#define NFRAMES 196
#define TPAD    208
#define BSZ     128
#define DLAT    1024
#define FIN     768
#define BM      128
#define BK      32
#define KSTEPS  (DLAT / BK)    // 32
#define MTILES  (FIN / BM)     // 6
#define NBLK    (MTILES * BSZ) // 768
#define NTHREADS 256

typedef short bf16x8 __attribute__((ext_vector_type(8)));
typedef float f32x4  __attribute__((ext_vector_type(4)));
typedef unsigned int u32x2 __attribute__((ext_vector_type(2)));
typedef unsigned int u32x4 __attribute__((ext_vector_type(4)));

__device__ __forceinline__ unsigned int pkbf(float lo, float hi) {
    unsigned short a = (unsigned short)__builtin_bit_cast(short, __float2bfloat16(lo));  // RNE
    unsigned short b = (unsigned short)__builtin_bit_cast(short, __float2bfloat16(hi));
    return (unsigned int)a | ((unsigned int)b << 16);
}

// barrier that does NOT drain vmcnt (prefetch global loads stay in flight)
#define BAR() do { asm volatile("s_waitcnt lgkmcnt(0)" ::: "memory"); \
                   __builtin_amdgcn_s_barrier(); } while (0)

template<int NF>
__device__ __forceinline__ void mfma_all(const short* __restrict__ Bp, const int* idxB,
                                         const bf16x8 (&af)[4], f32x4 (&acc)[4][7]) {
    #pragma unroll
    for (int nf = 0; nf < NF; ++nf) {
        bf16x8 bv = *reinterpret_cast<const bf16x8*>(&Bp[idxB[nf]]);
        #pragma unroll
        for (int f = 0; f < 4; ++f)
            acc[f][nf] = __builtin_amdgcn_mfma_f32_16x16x32_bf16(af[f], bv, acc[f][nf], 0, 0, 0);
    }
}

template<int NF>
__device__ __forceinline__ void epilogue(const f32x4 (&acc)[4][7], float* __restrict__ outB,
                                         const float* __restrict__ biasE, int fcb, int m0,
                                         int wr, int wc, int g, int lr) {
    #pragma unroll
    for (int f = 0; f < 4; ++f) {
        #pragma unroll
        for (int rr = 0; rr < 4; ++rr) {
            const int fcol = m0 + wr * 64 + f * 16 + g * 4 + rr;   // C row = (lane>>4)*4 + reg
            const float bb = biasE[fcol];
            const bool  val = fcol < fcb;
            #pragma unroll
            for (int nf = 0; nf < NF; ++nf) {
                const int t = wc * 112 + nf * 16 + lr;             // C col = lane&15
                if (t < NFRAMES)
                    outB[fcol * NFRAMES + t] = val ? (acc[f][nf][rr] + bb) : 0.f;
            }
        }
    }
}

__global__ __launch_bounds__(NTHREADS, 2)
void fused_expert_gemm(const float* __restrict__ X,      // (196,128,1024)
                       const int*   __restrict__ otypes, // (128)
                       const float* __restrict__ W,      // (16,1024,768)
                       const float* __restrict__ Bias,   // (16,768)
                       const int*   __restrict__ jc,     // (16)
                       float*       __restrict__ out)    // (128,768,196)
{
    __shared__ short As[2][BM * BK];    // [m][k], plain 64B rows
    __shared__ short Bs[2][TPAD * BK];  // [t][k], plain 64B rows

    // XCD chunk swizzle: 768 blocks, 96 consecutive logical (=16 samples) per XCD.
    const int hw      = blockIdx.x;
    const int logical = (hw & 7) * (NBLK / 8) + (hw >> 3);
    const int b       = logical / MTILES;
    const int mt      = logical - b * MTILES;
    const int m0      = mt * BM;

    const int tid = threadIdx.x;
    const int e   = otypes[b];
    const int fcb = jc[e] * 6;
    float* outB = out + (size_t)b * (FIN * NFRAMES);

    if (m0 >= fcb) {
        // fully masked tile: zero-fill 128x196 contiguous floats, skip GEMM + W fetch
        f32x4 zz = {0.f, 0.f, 0.f, 0.f};
        f32x4* dst = reinterpret_cast<f32x4*>(outB + m0 * NFRAMES);
        const int total = (BM * NFRAMES) / 4;   // 6272
        for (int i = tid; i < total; i += NTHREADS) dst[i] = zz;
        return;
    }

    const int wave = tid >> 6;
    const int lane = tid & 63;
    const int lr   = lane & 15;
    const int g    = lane >> 4;
    const int wr   = wave >> 1;   // M half (64 rows)
    const int wc   = wave & 1;    // N part: 0 -> frags 0..6 (t<112), 1 -> frags 7..12

    // A staging: thread owns 4k x 4m; load-rotation kbe spreads write banks
    const int mb  = tid & 31;
    const int kb  = tid >> 5;
    const int kbe = (kb + (mb >> 2)) & 7;
    // B staging: thread owns 16B k-chunk of one row; 4 passes x 64 rows
    const int ko = tid & 3;
    const int rw = tid >> 2;

    const f32x4* __restrict__ Xv = reinterpret_cast<const f32x4*>(X);
    const f32x4* __restrict__ Wv = reinterpret_cast<const f32x4*>(W);
    const f32x4 fz = {0.f, 0.f, 0.f, 0.f};

    f32x4 wa[4];      // W prefetch (4 k-rows x 4 m)
    f32x4 xb[4][2];   // X prefetch (4 passes x 8 k)

    int idxA[4], idxB[7];
    #pragma unroll
    for (int f = 0; f < 4; ++f)
        idxA[f] = (wr * 64 + f * 16 + lr) * BK + g * 8;
    #pragma unroll
    for (int nf = 0; nf < 7; ++nf)
        idxB[nf] = (wc * 112 + nf * 16 + lr) * BK + g * 8;   // wc=1 uses only nf<6

    f32x4 acc[4][7];
    #pragma unroll
    for (int f = 0; f < 4; ++f)
        #pragma unroll
        for (int nf = 0; nf < 7; ++nf) acc[f][nf] = fz;

    auto load_stage = [&](int kk) {
        #pragma unroll
        for (int i = 0; i < 4; ++i)
            wa[i] = Wv[(e * DLAT + kk + kbe * 4 + i) * (FIN / 4) + (m0 >> 2) + mb];
        #pragma unroll
        for (int p = 0; p < 4; ++p) {
            const int n = p * 64 + rw;
            if (n < NFRAMES) {
                const int base = (n * BSZ + b) * (DLAT / 4) + (kk >> 2) + ko * 2;
                xb[p][0] = Xv[base];
                xb[p][1] = Xv[base + 1];
            } else { xb[p][0] = fz; xb[p][1] = fz; }
        }
    };

    auto write_stage = [&](int buf) {
        #pragma unroll
        for (int jj = 0; jj < 4; ++jj) {
            const int r = (mb + jj) & 3;                 // rotate row order within quad
            u32x2 v = { pkbf(wa[0][r], wa[1][r]), pkbf(wa[2][r], wa[3][r]) };
            *reinterpret_cast<u32x2*>(&As[buf][(mb * 4 + r) * BK + kbe * 4]) = v;
        }
        #pragma unroll
        for (int p = 0; p < 4; ++p) {
            const int n = p * 64 + rw;
            if (n < TPAD) {
                u32x4 v = { pkbf(xb[p][0][0], xb[p][0][1]), pkbf(xb[p][0][2], xb[p][0][3]),
                            pkbf(xb[p][1][0], xb[p][1][1]), pkbf(xb[p][1][2], xb[p][1][3]) };
                *reinterpret_cast<u32x4*>(&Bs[buf][n * BK + ko * 8]) = v;
            }
        }
    };

    // Prologue: tile0 -> buf0; tile1 loads in flight
    load_stage(0);
    write_stage(0);
    load_stage(BK);
    BAR();

    // Main loop: ONE barrier per iter; double-buffered LDS.
    // Order: frag reads + MFMA first (B-reads never queue behind ds_writes),
    // then write tile j+1 into the other buffer, then issue loads for tile j+2.
    #pragma unroll 1
    for (int j = 0; j < KSTEPS; ++j) {
        const int cur = j & 1;
        bf16x8 af[4];
        #pragma unroll
        for (int f = 0; f < 4; ++f)
            af[f] = *reinterpret_cast<const bf16x8*>(&As[cur][idxA[f]]);

        if (wc == 0) mfma_all<7>(Bs[cur], idxB, af, acc);
        else         mfma_all<6>(Bs[cur], idxB, af, acc);

        if (j + 1 < KSTEPS) write_stage(cur ^ 1);
        if (j + 2 < KSTEPS) load_stage((j + 2) * BK);
        BAR();
    }

    const float* biasE = Bias + e * FIN;
    if (wc == 0) epilogue<7>(acc, outB, biasE, fcb, m0, wr, wc, g, lr);
    else         epilogue<6>(acc, outB, biasE, fcb, m0, wr, wc, g, lr);
}

extern "C" void kernel_launch(void* const* d_in, const int* in_sizes, int n_in,
                              void* d_out, int out_size, void* d_ws, size_t ws_size,
                              hipStream_t stream) {
    const float* X    = (const float*)d_in[0];
    const int*   ot   = (const int*)d_in[1];
    const float* W    = (const float*)d_in[2];
    const float* Bias = (const float*)d_in[3];
    const int*   jc   = (const int*)d_in[4];
    float*       out  = (float*)d_out;

    dim3 grid(NBLK);      // 768 = 128 samples x 6 M-tiles
    dim3 block(NTHREADS);
    hipLaunchKernelGGL(fused_expert_gemm, grid, block, 0, stream,
                       X, ot, W, Bias, jc, out);
}